// Round 1
// baseline (236.540 us; speedup 1.0000x reference)
//
#include <hip/hip_runtime.h>
#include <hip/hip_bf16.h>

typedef __bf16 bf16;
typedef __attribute__((ext_vector_type(8))) __bf16 b16x8;
typedef __attribute__((ext_vector_type(4))) float f32x4;

#define MFMA16(a, b, c) __builtin_amdgcn_mfma_f32_16x16x32_bf16((a), (b), (c), 0, 0, 0)

// ---------------- convert fp32 -> bf16, 8 elems/thread ----------------
__global__ void k_conv(const float* __restrict__ src, bf16* __restrict__ dst, int n) {
    int i = (blockIdx.x * blockDim.x + threadIdx.x) * 8;
    if (i >= n) return;
    f32x4 a = *(const f32x4*)(src + i);
    f32x4 b = *(const f32x4*)(src + i + 4);
    b16x8 o;
    o[0] = (bf16)a[0]; o[1] = (bf16)a[1]; o[2] = (bf16)a[2]; o[3] = (bf16)a[3];
    o[4] = (bf16)b[0]; o[5] = (bf16)b[1]; o[6] = (bf16)b[2]; o[7] = (bf16)b[3];
    *(b16x8*)(dst + i) = o;
}

// ---------------- v (B,Ns,256) fp32 -> vT[(b*8+h)*32+d][k] bf16 ----------------
__global__ void k_vtrans(const float* __restrict__ v, bf16* __restrict__ vT) {
    __shared__ __align__(16) bf16 sT[32][72];
    int tid = threadIdx.x;
    int bh = blockIdx.y, b = bh >> 3, h = bh & 7;
    int ns0 = blockIdx.x * 64;
    int ns = tid >> 2;
    int dp = (tid & 3) * 8;
    const float* sp = v + ((size_t)(b * 2048 + ns0 + ns)) * 256 + h * 32 + dp;
    f32x4 a = *(const f32x4*)sp;
    f32x4 c = *(const f32x4*)(sp + 4);
#pragma unroll
    for (int i = 0; i < 4; i++) sT[dp + i][ns] = (bf16)a[i];
#pragma unroll
    for (int i = 0; i < 4; i++) sT[dp + 4 + i][ns] = (bf16)c[i];
    __syncthreads();
    int d = tid >> 3;
    int nc = (tid & 7) * 8;
    b16x8 o = *(b16x8*)&sT[d][nc];
    *(b16x8*)(vT + ((size_t)bh * 32 + d) * 2048 + ns0 + nc) = o;
}

// ---------------- GEMM: out[M][256] = A[M][256](bf16) @ W[256][256]^T ----------------
template <bool BF16OUT>
__global__ void __launch_bounds__(256) k_gemm(const bf16* __restrict__ A,
                                              const bf16* __restrict__ Bm,
                                              const float* __restrict__ bias,
                                              bf16* __restrict__ outb,
                                              float* __restrict__ outf) {
    __shared__ __align__(16) bf16 sA[64][40];
    __shared__ __align__(16) bf16 sB[64][40];
    int tid = threadIdx.x;
    int w = tid >> 6, l = tid & 63, lg = l >> 4, ll = l & 15;
    int wm = w >> 1, wn = w & 1;
    int m0 = blockIdx.x * 64, n0 = blockIdx.y * 64;
    f32x4 acc[2][2] = {};
    int ar = tid >> 2, ac = (tid & 3) * 8;
#pragma unroll
    for (int k0 = 0; k0 < 256; k0 += 32) {
        __syncthreads();
        *(b16x8*)&sA[ar][ac] = *(const b16x8*)(A + (size_t)(m0 + ar) * 256 + k0 + ac);
        *(b16x8*)&sB[ar][ac] = *(const b16x8*)(Bm + (size_t)(n0 + ar) * 256 + k0 + ac);
        __syncthreads();
        b16x8 af[2], bfr[2];
#pragma unroll
        for (int f = 0; f < 2; f++) {
            af[f] = *(b16x8*)&sA[wm * 32 + f * 16 + ll][8 * lg];
            bfr[f] = *(b16x8*)&sB[wn * 32 + f * 16 + ll][8 * lg];
        }
#pragma unroll
        for (int i = 0; i < 2; i++)
#pragma unroll
            for (int j = 0; j < 2; j++) acc[i][j] = MFMA16(af[i], bfr[j], acc[i][j]);
    }
#pragma unroll
    for (int i = 0; i < 2; i++)
#pragma unroll
        for (int j = 0; j < 2; j++) {
            int row = m0 + wm * 32 + i * 16 + lg * 4;
            int col = n0 + wn * 32 + j * 16 + ll;
#pragma unroll
            for (int r = 0; r < 4; r++) {
                if constexpr (BF16OUT)
                    outb[(size_t)(row + r) * 256 + col] = (bf16)acc[i][j][r];
                else
                    outf[(size_t)(row + r) * 256 + col] = acc[i][j][r] + bias[col];
            }
        }
}

// ---------------- attention pass 1: O = softmax(QK^T*t+mask) @ V, plus row-sum l ------
// no max-subtraction: scores ~ N(0,1), masked -> exp underflows to exactly 0 (matches ref)
__global__ void __launch_bounds__(256) k_attn_flash(const bf16* __restrict__ ph,
                                                    const bf16* __restrict__ vT,
                                                    const int* __restrict__ svalid,
                                                    bf16* __restrict__ xO,
                                                    float* __restrict__ lbuf) {
    __shared__ __align__(16) bf16 sK[64][40];
    __shared__ __align__(16) bf16 sV[32][72];
    __shared__ __align__(16) bf16 sP[4][16][72];
    const float temp = 0.17677669529663687f;  // 1/sqrt(32)
    int tid = threadIdx.x;
    int w = tid >> 6, l = tid & 63, lg = l >> 4, ll = l & 15;
    int bh = blockIdx.y, b = bh >> 3, h = bh & 7;
    int qt = blockIdx.x;
    int qrow0 = qt * 64 + w * 16;
    b16x8 qf = *(const b16x8*)(ph + (size_t)(b * 2048 + qrow0 + ll) * 256 + h * 32 + 8 * lg);
    f32x4 o[2] = {};
    float lacc[4] = {0.f, 0.f, 0.f, 0.f};
    int kr = tid >> 2, kc = (tid & 3) * 8;
    int dr = tid >> 3, nc2 = (tid & 7) * 8;
    for (int kt = 0; kt < 2048; kt += 64) {
        __syncthreads();
        *(b16x8*)&sK[kr][kc] =
            *(const b16x8*)(ph + (size_t)(8192 + b * 2048 + kt + kr) * 256 + h * 32 + kc);
        *(b16x8*)&sV[dr][nc2] = *(const b16x8*)(vT + ((size_t)bh * 32 + dr) * 2048 + kt + nc2);
        __syncthreads();
        f32x4 s[4];
#pragma unroll
        for (int n = 0; n < 4; n++) {
            b16x8 kf = *(b16x8*)&sK[n * 16 + ll][8 * lg];
            f32x4 z = {};
            s[n] = MFMA16(qf, kf, z);
        }
#pragma unroll
        for (int n = 0; n < 4; n++) {
            float madd = -1000.f * (float)svalid[b * 2048 + kt + n * 16 + ll];
#pragma unroll
            for (int r = 0; r < 4; r++) {
                float p = __expf(s[n][r] * temp + madd);
                lacc[r] += p;
                sP[w][lg * 4 + r][n * 16 + ll] = (bf16)p;
            }
        }
#pragma unroll
        for (int ks = 0; ks < 2; ks++) {
            b16x8 pf = *(b16x8*)&sP[w][ll][ks * 32 + 8 * lg];
#pragma unroll
            for (int j = 0; j < 2; j++) {
                b16x8 vf = *(b16x8*)&sV[j * 16 + ll][ks * 32 + 8 * lg];
                o[j] = MFMA16(pf, vf, o[j]);
            }
        }
    }
#pragma unroll
    for (int r = 0; r < 4; r++) {
#pragma unroll
        for (int off = 1; off < 16; off <<= 1) lacc[r] += __shfl_xor(lacc[r], off, 64);
    }
#pragma unroll
    for (int r = 0; r < 4; r++) {
        float rin = 1.f / lacc[r];
        int row = b * 2048 + qrow0 + lg * 4 + r;
        if (ll == 0) lbuf[(size_t)bh * 2048 + qrow0 + lg * 4 + r] = lacc[r];
#pragma unroll
        for (int j = 0; j < 2; j++)
            xO[(size_t)row * 256 + h * 32 + j * 16 + ll] = (bf16)(o[j][r] * rin);
    }
}

// ---------------- attention pass 2: recompute scores, write normalized attn fp32 ------
__global__ void __launch_bounds__(256) k_attn_write(const bf16* __restrict__ ph,
                                                    const int* __restrict__ svalid,
                                                    const float* __restrict__ lbuf,
                                                    float* __restrict__ attn) {
    __shared__ __align__(16) bf16 sK[64][40];
    const float temp = 0.17677669529663687f;
    int tid = threadIdx.x;
    int w = tid >> 6, l = tid & 63, lg = l >> 4, ll = l & 15;
    int bh = blockIdx.y, b = bh >> 3, h = bh & 7;
    int qt = blockIdx.x;
    int qrow0 = qt * 64 + w * 16;
    b16x8 qf = *(const b16x8*)(ph + (size_t)(b * 2048 + qrow0 + ll) * 256 + h * 32 + 8 * lg);
    float linv[4];
#pragma unroll
    for (int r = 0; r < 4; r++)
        linv[r] = 1.f / lbuf[(size_t)bh * 2048 + qrow0 + lg * 4 + r];
    int kr = tid >> 2, kc = (tid & 3) * 8;
    for (int kt = 0; kt < 2048; kt += 64) {
        __syncthreads();
        *(b16x8*)&sK[kr][kc] =
            *(const b16x8*)(ph + (size_t)(8192 + b * 2048 + kt + kr) * 256 + h * 32 + kc);
        __syncthreads();
        f32x4 s[4];
#pragma unroll
        for (int n = 0; n < 4; n++) {
            b16x8 kf = *(b16x8*)&sK[n * 16 + ll][8 * lg];
            f32x4 z = {};
            s[n] = MFMA16(qf, kf, z);
        }
#pragma unroll
        for (int n = 0; n < 4; n++) {
            float madd = -1000.f * (float)svalid[b * 2048 + kt + n * 16 + ll];
#pragma unroll
            for (int r = 0; r < 4; r++) {
                float p = __expf(s[n][r] * temp + madd) * linv[r];
                attn[((size_t)(bh * 2048 + qrow0 + lg * 4 + r)) * 2048 + kt + n * 16 + ll] = p;
            }
        }
    }
}

// ---------------- fused residual add + LayerNorm (row = 256) ----------------
__global__ void __launch_bounds__(256) k_ln(const float* __restrict__ y,
                                            const float* __restrict__ idt,
                                            const float* __restrict__ lnw,
                                            const float* __restrict__ lnb,
                                            float* __restrict__ out) {
    int tid = threadIdx.x;
    int w = tid >> 6, l = tid & 63;
    int row = blockIdx.x * 4 + w;
    f32x4 xv = *(const f32x4*)(y + (size_t)row * 256 + l * 4);
    f32x4 iv = *(const f32x4*)(idt + (size_t)row * 256 + l * 4);
#pragma unroll
    for (int c = 0; c < 4; c++) xv[c] += iv[c];
    float s = xv[0] + xv[1] + xv[2] + xv[3];
    float s2 = xv[0] * xv[0] + xv[1] * xv[1] + xv[2] * xv[2] + xv[3] * xv[3];
#pragma unroll
    for (int off = 1; off < 64; off <<= 1) {
        s += __shfl_xor(s, off, 64);
        s2 += __shfl_xor(s2, off, 64);
    }
    float mu = s * (1.f / 256.f);
    float var = s2 * (1.f / 256.f) - mu * mu;
    float rstd = rsqrtf(var + 1e-5f);
    f32x4 wv = *(const f32x4*)(lnw + l * 4);
    f32x4 bv = *(const f32x4*)(lnb + l * 4);
    f32x4 ov;
#pragma unroll
    for (int c = 0; c < 4; c++) ov[c] = (xv[c] - mu) * rstd * wv[c] + bv[c];
    *(f32x4*)(out + (size_t)row * 256 + l * 4) = ov;
}

extern "C" void kernel_launch(void* const* d_in, const int* in_sizes, int n_in,
                              void* d_out, int out_size, void* d_ws, size_t ws_size,
                              hipStream_t stream) {
    const float* k_in = (const float*)d_in[0];
    const float* v_in = (const float*)d_in[1];
    const float* q_in = (const float*)d_in[2];
    const float* idt  = (const float*)d_in[3];
    const int* svalid = (const int*)d_in[4];
    const float* Wqk  = (const float*)d_in[5];
    const float* Wfc  = (const float*)d_in[6];
    const float* bfc  = (const float*)d_in[7];
    const float* lnw  = (const float*)d_in[8];
    const float* lnb  = (const float*)d_in[9];

    float* out_ln = (float*)d_out;
    float* attn = out_ln + 2097152;  // B*Nq*D floats, attn follows

    // persistent scratch (must survive until k_attn_write): 12.8 MB in ws
    char* ws = (char*)d_ws;
    bf16* ph    = (bf16*)ws;                   // 16384*256 bf16 (proj q rows 0.., k rows 8192..)
    bf16* vT    = (bf16*)(ws + 8388608);       // 32*32*2048 bf16
    float* lbuf = (float*)(ws + 12582912);     // 65536 f32
    bf16* Wqkb  = (bf16*)(ws + 12845056);      // 65536 bf16
    bf16* Wfcb  = (bf16*)(ws + 12976128);      // 65536 bf16

    // transient scratch parked in the attn output region (dead before k_attn_write)
    char* sc = (char*)attn;
    bf16* xb = (bf16*)sc;                      // 16384*256 bf16 (q,k cast)
    bf16* xO = (bf16*)(sc + 8388608);          // 8192*256 bf16 (attn@V)
    float* y = (float*)(sc + 12582912);        // 8192*256 f32 (FC out)

    k_conv<<<1024, 256, 0, stream>>>(q_in, xb, 2097152);
    k_conv<<<1024, 256, 0, stream>>>(k_in, xb + 2097152, 2097152);
    k_conv<<<32, 256, 0, stream>>>(Wqk, Wqkb, 65536);
    k_conv<<<32, 256, 0, stream>>>(Wfc, Wfcb, 65536);
    k_vtrans<<<dim3(32, 32), 256, 0, stream>>>(v_in, vT);

    k_gemm<true><<<dim3(256, 4), 256, 0, stream>>>(xb, Wqkb, nullptr, ph, nullptr);
    k_attn_flash<<<dim3(32, 32), 256, 0, stream>>>(ph, vT, svalid, xO, lbuf);
    k_gemm<false><<<dim3(128, 4), 256, 0, stream>>>(xO, Wfcb, bfc, nullptr, y);
    k_ln<<<2048, 256, 0, stream>>>(y, idt, lnw, lnb, out_ln);
    k_attn_write<<<dim3(32, 32), 256, 0, stream>>>(ph, svalid, lbuf, attn);
}

// Round 2
// 224.149 us; speedup vs baseline: 1.0553x; 1.0553x over previous
//
#include <hip/hip_runtime.h>
#include <hip/hip_bf16.h>

typedef __bf16 bf16;
typedef __attribute__((ext_vector_type(8))) __bf16 b16x8;
typedef __attribute__((ext_vector_type(4))) float f32x4;

#define MFMA16(a, b, c) __builtin_amdgcn_mfma_f32_16x16x32_bf16((a), (b), (c), 0, 0, 0)

// ---------------- weights fp32 -> bf16 (both W in one launch) ----------------
__global__ void k_convW(const float* __restrict__ w1, const float* __restrict__ w2,
                        bf16* __restrict__ o1, bf16* __restrict__ o2) {
    int i = (blockIdx.x * 256 + threadIdx.x) * 8;
    const float* s = (i < 65536) ? w1 + i : w2 + (i - 65536);
    bf16* d = (i < 65536) ? o1 + i : o2 + (i - 65536);
    f32x4 a = *(const f32x4*)s;
    f32x4 b = *(const f32x4*)(s + 4);
    b16x8 o;
    o[0] = (bf16)a[0]; o[1] = (bf16)a[1]; o[2] = (bf16)a[2]; o[3] = (bf16)a[3];
    o[4] = (bf16)b[0]; o[5] = (bf16)b[1]; o[6] = (bf16)b[2]; o[7] = (bf16)b[3];
    *(b16x8*)d = o;
}

// ---------------- v (B,Ns,256) fp32 -> vT[(b*8+h)*32+d][k] bf16 ----------------
__global__ void k_vtrans(const float* __restrict__ v, bf16* __restrict__ vT) {
    __shared__ __align__(16) bf16 sT[32][72];
    int tid = threadIdx.x;
    int bh = blockIdx.y, b = bh >> 3, h = bh & 7;
    int ns0 = blockIdx.x * 64;
    int ns = tid >> 2;
    int dp = (tid & 3) * 8;
    const float* sp = v + ((size_t)(b * 2048 + ns0 + ns)) * 256 + h * 32 + dp;
    f32x4 a = *(const f32x4*)sp;
    f32x4 c = *(const f32x4*)(sp + 4);
#pragma unroll
    for (int i = 0; i < 4; i++) sT[dp + i][ns] = (bf16)a[i];
#pragma unroll
    for (int i = 0; i < 4; i++) sT[dp + 4 + i][ns] = (bf16)c[i];
    __syncthreads();
    int d = tid >> 3;
    int nc = (tid & 7) * 8;
    b16x8 o = *(b16x8*)&sT[d][nc];
    *(b16x8*)(vT + ((size_t)bh * 32 + d) * 2048 + ns0 + nc) = o;
}

// ---------------- proj GEMM with fused fp32->bf16 A staging ----------------
// ph[m][256] = [q;k][m][256] @ Wqk^T   (m in 0..16383, q rows first)
__global__ void __launch_bounds__(256) k_proj(const float* __restrict__ q,
                                              const float* __restrict__ kk,
                                              const bf16* __restrict__ W,
                                              bf16* __restrict__ ph) {
    __shared__ __align__(16) bf16 sA[64][40];
    __shared__ __align__(16) bf16 sB[64][40];
    int tid = threadIdx.x;
    int w = tid >> 6, l = tid & 63, lg = l >> 4, ll = l & 15;
    int wm = w >> 1, wn = w & 1;
    int m0 = blockIdx.x * 64, n0 = blockIdx.y * 64;
    const float* A = (m0 < 8192) ? q + (size_t)m0 * 256 : kk + (size_t)(m0 - 8192) * 256;
    f32x4 acc[2][2] = {};
    int ar = tid >> 2, ac = (tid & 3) * 8;
#pragma unroll
    for (int k0 = 0; k0 < 256; k0 += 32) {
        __syncthreads();
        f32x4 a0 = *(const f32x4*)(A + (size_t)ar * 256 + k0 + ac);
        f32x4 a1 = *(const f32x4*)(A + (size_t)ar * 256 + k0 + ac + 4);
        b16x8 av;
#pragma unroll
        for (int i = 0; i < 4; i++) { av[i] = (bf16)a0[i]; av[4 + i] = (bf16)a1[i]; }
        *(b16x8*)&sA[ar][ac] = av;
        *(b16x8*)&sB[ar][ac] = *(const b16x8*)(W + (size_t)(n0 + ar) * 256 + k0 + ac);
        __syncthreads();
        b16x8 af[2], bfr[2];
#pragma unroll
        for (int f = 0; f < 2; f++) {
            af[f] = *(b16x8*)&sA[wm * 32 + f * 16 + ll][8 * lg];
            bfr[f] = *(b16x8*)&sB[wn * 32 + f * 16 + ll][8 * lg];
        }
#pragma unroll
        for (int i = 0; i < 2; i++)
#pragma unroll
            for (int j = 0; j < 2; j++) acc[i][j] = MFMA16(af[i], bfr[j], acc[i][j]);
    }
#pragma unroll
    for (int i = 0; i < 2; i++)
#pragma unroll
        for (int j = 0; j < 2; j++) {
            int row = m0 + wm * 32 + i * 16 + lg * 4;
            int col = n0 + wn * 32 + j * 16 + ll;
#pragma unroll
            for (int r = 0; r < 4; r++)
                ph[(size_t)(row + r) * 256 + col] = (bf16)acc[i][j][r];
        }
}

// ---------------- attention pass 1: O = softmax(QK^T*t+mask) @ V, row-sum l ----------
__global__ void __launch_bounds__(256) k_attn_flash(const bf16* __restrict__ ph,
                                                    const bf16* __restrict__ vT,
                                                    const int* __restrict__ svalid,
                                                    bf16* __restrict__ xO,
                                                    float* __restrict__ lbuf) {
    __shared__ __align__(16) bf16 sK[64][40];
    __shared__ __align__(16) bf16 sV[32][72];
    __shared__ __align__(16) bf16 sP[4][16][72];
    __shared__ float smadd[64];
    const float temp = 0.17677669529663687f;  // 1/sqrt(32)
    int tid = threadIdx.x;
    int w = tid >> 6, l = tid & 63, lg = l >> 4, ll = l & 15;
    int bh = blockIdx.y, b = bh >> 3, h = bh & 7;
    int qt = blockIdx.x;
    int qrow0 = qt * 64 + w * 16;
    b16x8 qf = *(const b16x8*)(ph + (size_t)(b * 2048 + qrow0 + ll) * 256 + h * 32 + 8 * lg);
    f32x4 o[2] = {};
    float lacc[4] = {0.f, 0.f, 0.f, 0.f};
    int kr = tid >> 2, kc = (tid & 3) * 8;
    int dr = tid >> 3, nc2 = (tid & 7) * 8;
    for (int kt = 0; kt < 2048; kt += 64) {
        __syncthreads();
        *(b16x8*)&sK[kr][kc] =
            *(const b16x8*)(ph + (size_t)(8192 + b * 2048 + kt + kr) * 256 + h * 32 + kc);
        *(b16x8*)&sV[dr][nc2] = *(const b16x8*)(vT + ((size_t)bh * 32 + dr) * 2048 + kt + nc2);
        if (tid < 64) smadd[tid] = -1000.f * (float)svalid[b * 2048 + kt + tid];
        __syncthreads();
        f32x4 s[4];
#pragma unroll
        for (int n = 0; n < 4; n++) {
            b16x8 kf = *(b16x8*)&sK[n * 16 + ll][8 * lg];
            f32x4 z = {};
            s[n] = MFMA16(qf, kf, z);
        }
#pragma unroll
        for (int n = 0; n < 4; n++) {
            float madd = smadd[n * 16 + ll];
#pragma unroll
            for (int r = 0; r < 4; r++) {
                float p = __expf(s[n][r] * temp + madd);
                lacc[r] += p;
                sP[w][lg * 4 + r][n * 16 + ll] = (bf16)p;
            }
        }
#pragma unroll
        for (int ks = 0; ks < 2; ks++) {
            b16x8 pf = *(b16x8*)&sP[w][ll][ks * 32 + 8 * lg];
#pragma unroll
            for (int j = 0; j < 2; j++) {
                b16x8 vf = *(b16x8*)&sV[j * 16 + ll][ks * 32 + 8 * lg];
                o[j] = MFMA16(pf, vf, o[j]);
            }
        }
    }
#pragma unroll
    for (int r = 0; r < 4; r++) {
#pragma unroll
        for (int off = 1; off < 16; off <<= 1) lacc[r] += __shfl_xor(lacc[r], off, 64);
    }
#pragma unroll
    for (int r = 0; r < 4; r++) {
        float rin = 1.f / lacc[r];
        int row = b * 2048 + qrow0 + lg * 4 + r;
        if (ll == 0) lbuf[(size_t)bh * 2048 + qrow0 + lg * 4 + r] = lacc[r];
#pragma unroll
        for (int j = 0; j < 2; j++)
            xO[(size_t)row * 256 + h * 32 + j * 16 + ll] = (bf16)(o[j][r] * rin);
    }
}

// ---------------- fused tail: FC GEMM (+bias+idt) || attn materialization ----------
__global__ void __launch_bounds__(256) k_tail(const bf16* __restrict__ xO,
                                              const bf16* __restrict__ Wfc,
                                              const float* __restrict__ bias,
                                              const float* __restrict__ idt,
                                              float* __restrict__ y,
                                              const bf16* __restrict__ ph,
                                              const int* __restrict__ svalid,
                                              const float* __restrict__ lbuf,
                                              float* __restrict__ attn) {
    __shared__ __align__(16) char smem[10624];
    int tid = threadIdx.x;
    int w = tid >> 6, l = tid & 63, lg = l >> 4, ll = l & 15;
    if (blockIdx.x < 512) {
        // ---- FC: y[m][n] = xO[m][:] @ Wfc[n][:] + bias[n] + idt[m][n] ----
        bf16(*sA)[40] = (bf16(*)[40])smem;
        bf16(*sB)[40] = (bf16(*)[40])(smem + 5120);
        int wm = w >> 1, wn = w & 1;
        int m0 = (blockIdx.x >> 2) * 64, n0 = (blockIdx.x & 3) * 64;
        f32x4 acc[2][2] = {};
        int ar = tid >> 2, ac = (tid & 3) * 8;
#pragma unroll
        for (int k0 = 0; k0 < 256; k0 += 32) {
            __syncthreads();
            *(b16x8*)&sA[ar][ac] = *(const b16x8*)(xO + (size_t)(m0 + ar) * 256 + k0 + ac);
            *(b16x8*)&sB[ar][ac] = *(const b16x8*)(Wfc + (size_t)(n0 + ar) * 256 + k0 + ac);
            __syncthreads();
            b16x8 af[2], bfr[2];
#pragma unroll
            for (int f = 0; f < 2; f++) {
                af[f] = *(b16x8*)&sA[wm * 32 + f * 16 + ll][8 * lg];
                bfr[f] = *(b16x8*)&sB[wn * 32 + f * 16 + ll][8 * lg];
            }
#pragma unroll
            for (int i = 0; i < 2; i++)
#pragma unroll
                for (int j = 0; j < 2; j++) acc[i][j] = MFMA16(af[i], bfr[j], acc[i][j]);
        }
#pragma unroll
        for (int i = 0; i < 2; i++)
#pragma unroll
            for (int j = 0; j < 2; j++) {
                int row = m0 + wm * 32 + i * 16 + lg * 4;
                int col = n0 + wn * 32 + j * 16 + ll;
#pragma unroll
                for (int r = 0; r < 4; r++)
                    y[(size_t)(row + r) * 256 + col] =
                        acc[i][j][r] + bias[col] + idt[(size_t)(row + r) * 256 + col];
            }
    } else {
        // ---- attn write: recompute scores, write normalized fp32 ----
        bf16(*sK)[40] = (bf16(*)[40])smem;
        float* smadd = (float*)(smem + 5120);
        const float temp = 0.17677669529663687f;
        int idx = blockIdx.x - 512;
        int qt = idx & 31, bh = idx >> 5;
        int b = bh >> 3, h = bh & 7;
        int qrow0 = qt * 64 + w * 16;
        b16x8 qf = *(const b16x8*)(ph + (size_t)(b * 2048 + qrow0 + ll) * 256 + h * 32 + 8 * lg);
        float linv[4];
#pragma unroll
        for (int r = 0; r < 4; r++)
            linv[r] = 1.f / lbuf[(size_t)bh * 2048 + qrow0 + lg * 4 + r];
        int kr = tid >> 2, kc = (tid & 3) * 8;
        for (int kt = 0; kt < 2048; kt += 64) {
            __syncthreads();
            *(b16x8*)&sK[kr][kc] =
                *(const b16x8*)(ph + (size_t)(8192 + b * 2048 + kt + kr) * 256 + h * 32 + kc);
            if (tid < 64) smadd[tid] = -1000.f * (float)svalid[b * 2048 + kt + tid];
            __syncthreads();
            f32x4 s[4];
#pragma unroll
            for (int n = 0; n < 4; n++) {
                b16x8 kf = *(b16x8*)&sK[n * 16 + ll][8 * lg];
                f32x4 z = {};
                s[n] = MFMA16(qf, kf, z);
            }
#pragma unroll
            for (int n = 0; n < 4; n++) {
                float madd = smadd[n * 16 + ll];
#pragma unroll
                for (int r = 0; r < 4; r++) {
                    float p = __expf(s[n][r] * temp + madd) * linv[r];
                    attn[((size_t)(bh * 2048 + qrow0 + lg * 4 + r)) * 2048 + kt + n * 16 + ll] = p;
                }
            }
        }
    }
}

// ---------------- LayerNorm in place (x already = FCout+bias+idt) ----------------
__global__ void __launch_bounds__(256) k_ln(float* __restrict__ x,
                                            const float* __restrict__ lnw,
                                            const float* __restrict__ lnb) {
    int tid = threadIdx.x;
    int w = tid >> 6, l = tid & 63;
    int row = blockIdx.x * 4 + w;
    f32x4 xv = *(const f32x4*)(x + (size_t)row * 256 + l * 4);
    float s = xv[0] + xv[1] + xv[2] + xv[3];
    float s2 = xv[0] * xv[0] + xv[1] * xv[1] + xv[2] * xv[2] + xv[3] * xv[3];
#pragma unroll
    for (int off = 1; off < 64; off <<= 1) {
        s += __shfl_xor(s, off, 64);
        s2 += __shfl_xor(s2, off, 64);
    }
    float mu = s * (1.f / 256.f);
    float var = s2 * (1.f / 256.f) - mu * mu;
    float rstd = rsqrtf(var + 1e-5f);
    f32x4 wv = *(const f32x4*)(lnw + l * 4);
    f32x4 bv = *(const f32x4*)(lnb + l * 4);
    f32x4 ov;
#pragma unroll
    for (int c = 0; c < 4; c++) ov[c] = (xv[c] - mu) * rstd * wv[c] + bv[c];
    *(f32x4*)(x + (size_t)row * 256 + l * 4) = ov;
}

extern "C" void kernel_launch(void* const* d_in, const int* in_sizes, int n_in,
                              void* d_out, int out_size, void* d_ws, size_t ws_size,
                              hipStream_t stream) {
    const float* k_in = (const float*)d_in[0];
    const float* v_in = (const float*)d_in[1];
    const float* q_in = (const float*)d_in[2];
    const float* idt  = (const float*)d_in[3];
    const int* svalid = (const int*)d_in[4];
    const float* Wqk  = (const float*)d_in[5];
    const float* Wfc  = (const float*)d_in[6];
    const float* bfc  = (const float*)d_in[7];
    const float* lnw  = (const float*)d_in[8];
    const float* lnb  = (const float*)d_in[9];

    float* out_ln = (float*)d_out;               // 8192*256 f32; doubles as y (LN in place)
    float* attn = out_ln + 2097152;              // (B*H, Nq, Ns) f32

    // workspace (13.1 MB, same budget as the passing round)
    char* ws = (char*)d_ws;
    bf16* ph    = (bf16*)ws;                     // 16384*256 bf16 (q rows 0.., k rows 8192..)
    bf16* xO    = (bf16*)(ws + 8388608);         // 8192*256 bf16 (attn@V, normalized)
    float* lbuf = (float*)(ws + 12582912);       // 65536 f32 row sums
    bf16* Wqkb  = (bf16*)(ws + 12845056);        // 65536 bf16
    bf16* Wfcb  = (bf16*)(ws + 12976128);        // 65536 bf16

    // vT parks in the attn output region (dead before k_tail's attn writes)
    bf16* vT = (bf16*)attn;                      // 32*32*2048 bf16 = 4 MB

    k_convW<<<64, 256, 0, stream>>>(Wqk, Wfc, Wqkb, Wfcb);
    k_vtrans<<<dim3(32, 32), 256, 0, stream>>>(v_in, vT);
    k_proj<<<dim3(256, 4), 256, 0, stream>>>(q_in, k_in, Wqkb, ph);
    k_attn_flash<<<dim3(32, 32), 256, 0, stream>>>(ph, vT, svalid, xO, lbuf);
    k_tail<<<1536, 256, 0, stream>>>(xO, Wfcb, bfc, idt, out_ln, ph, svalid, lbuf, attn);
    k_ln<<<2048, 256, 0, stream>>>(out_ln, lnw, lnb);
}